// Round 15
// baseline (257.432 us; speedup 1.0000x reference)
//
#include <hip/hip_runtime.h>

#define N_NODES 40000
#define N_EDGES 640000
#define N_GRAPHS 64
#define BCAP 64   // bucket capacity per node (P[deg>64] ~ 1e-26 at E[deg]=16)

typedef unsigned short u16;
typedef unsigned int u32;
typedef __attribute__((ext_vector_type(8))) short bf16x8;
typedef __attribute__((ext_vector_type(4))) float f32x4;

static inline int cdiv(long long a, int b) { return (int)((a + b - 1) / b); }

// ---------------- bf16 helpers (bf16 = top 16 bits of fp32) ----------------
__device__ __forceinline__ u16 f2bf(float f) {
    u32 u = __float_as_uint(f);
    u32 r = (u + 0x7fffu + ((u >> 16) & 1u)) >> 16;  // round-to-nearest-even
    return (u16)r;
}
__device__ __forceinline__ u32 packpair(float a, float b) {
    return (u32)f2bf(a) | ((u32)f2bf(b) << 16);
}
__device__ __forceinline__ void unpack8(uint4 q, float* o) {
    o[0] = __uint_as_float(q.x << 16); o[1] = __uint_as_float(q.x & 0xffff0000u);
    o[2] = __uint_as_float(q.y << 16); o[3] = __uint_as_float(q.y & 0xffff0000u);
    o[4] = __uint_as_float(q.z << 16); o[5] = __uint_as_float(q.z & 0xffff0000u);
    o[6] = __uint_as_float(q.w << 16); o[7] = __uint_as_float(q.w & 0xffff0000u);
}

// ---------------- weight packing into MFMA B-fragment layout ---------------
__device__ __forceinline__ void pack_one(int idx, int KS, int Kreal, int FOUT,
                                         const float* __restrict__ wrel,
                                         const float* __restrict__ wroot,
                                         u16* __restrict__ out) {
    int j = idx & 7;
    int lane = (idx >> 3) & 63;
    int rest = idx >> 9;
    int nt = rest / KS, ks = rest - nt * KS;
    int k = ks * 32 + (lane >> 4) * 8 + j;
    int col = nt * 16 + (lane & 15);
    float v = 0.f;
    if (k < Kreal / 2) v = wrel[k * FOUT + col];
    else if (k < Kreal) v = wroot[(k - Kreal / 2) * FOUT + col];
    out[idx] = f2bf(v);
}

// ---- prep: convert x, pack w2-4, zero deg/S, precompute M = Wstk5@w_lin ----
__global__ __launch_bounds__(256) void prep_kernel(
        const float* __restrict__ x, u16* __restrict__ xbf,
        const float* __restrict__ wr2, const float* __restrict__ wo2,
        const float* __restrict__ wr3, const float* __restrict__ wo3,
        const float* __restrict__ wr4, const float* __restrict__ wo4,
        const float* __restrict__ wr5, const float* __restrict__ wo5,
        const float* __restrict__ br5, const float* __restrict__ w_lin,
        u16* __restrict__ p2, u16* __restrict__ p3, u16* __restrict__ p4,
        int* __restrict__ deg, float* __restrict__ Szero,
        float* __restrict__ M, float* __restrict__ bb) {
    int tid = blockIdx.x * 256 + threadIdx.x;
    if (tid < 40000) {
        int n = tid;
        float v[8];
        #pragma unroll
        for (int i = 0; i < 7; ++i) v[i] = x[n * 7 + i];
        v[7] = 0.f;
        uint4 q;
        q.x = packpair(v[0], v[1]); q.y = packpair(v[2], v[3]);
        q.z = packpair(v[4], v[5]); q.w = packpair(v[6], v[7]);
        *(uint4*)(xbf + (long long)n * 8) = q;
    } else if (tid < 45632) {
        int t = tid - 40000;
        if (t < 512)        pack_one(t,        1, 16, 16, wr2, wo2, p2);
        else if (t < 1536)  pack_one(t - 512,  1, 32, 32, wr3, wo3, p3);
        else                pack_one(t - 1536, 2, 64, 64, wr4, wo4, p4);
    } else if (tid < 85632) {
        deg[tid - 45632] = 0;
    } else if (tid < 93888) {
        Szero[tid - 85632] = 0.f;              // S_rel | S_root | cnt (8256 floats)
    } else if (tid < 94144) {
        int t = tid - 93888;                   // M[k][c], k=t>>1, c=t&1
        int k = t >> 1, c = t & 1;
        const float* wk = (k < 64) ? (wr5 + k * 128) : (wo5 + (k - 64) * 128);
        float a = 0.f;
        for (int j = 0; j < 128; ++j) a += wk[j] * w_lin[j * 2 + c];
        M[t] = a;
    } else if (tid < 94146) {
        int c = tid - 94144;                   // bb[c] = b_rel5 . w_lin[:,c]
        float a = 0.f;
        for (int j = 0; j < 128; ++j) a += br5[j] * w_lin[j * 2 + c];
        bb[c] = a;
    }
}

// ---------------- bucket CSR: one-pass scatter (no hist/scan) --------------
__global__ __launch_bounds__(256) void scatter_bucket(const int* __restrict__ src,
                                                      const int* __restrict__ dst,
                                                      const float* __restrict__ ew,
                                                      int* __restrict__ deg,
                                                      int2* __restrict__ pair) {
    int e = blockIdx.x * 256 + threadIdx.x;
    if (e >= N_EDGES) return;
    int d = dst[e];
    int pos = atomicAdd(&deg[d], 1);
    if (pos < BCAP) {
        int2 q;
        q.x = src[e];
        q.y = __float_as_int(ew[e]);
        pair[(long long)d * BCAP + pos] = q;
    }
}

// ---------------- layer 1 fused: gather (FIN=8) + node update --------------
__global__ __launch_bounds__(256) void gather_node1(const u16* __restrict__ xbf,
                                                    const int* __restrict__ deg,
                                                    const int2* __restrict__ pair,
                                                    const float* __restrict__ wr,
                                                    const float* __restrict__ br,
                                                    const float* __restrict__ wo,
                                                    u16* __restrict__ h2) {
    __shared__ float swr[56], swo[56], sb[8];
    if (threadIdx.x < 56) { swr[threadIdx.x] = wr[threadIdx.x]; swo[threadIdx.x] = wo[threadIdx.x]; }
    if (threadIdx.x < 8) sb[threadIdx.x] = br[threadIdx.x];
    __syncthreads();
    int tid = blockIdx.x * 256 + threadIdx.x;
    int n = tid >> 3;
    if (n >= N_NODES) return;
    int s3 = tid & 7;
    int dn = deg[n]; if (dn > BCAP) dn = BCAP;
    const int2* row = pair + (long long)n * BCAP;
    // full prefetch: <= 8 edges per lane
    int2 q[8];
    #pragma unroll
    for (int i = 0; i < 8; ++i) {
        int p = s3 + i * 8;
        if (p < dn) q[i] = row[p];
    }
    uint4 rq[8];
    #pragma unroll
    for (int i = 0; i < 8; ++i) {
        int p = s3 + i * 8;
        if (p < dn) rq[i] = *(const uint4*)(xbf + (long long)q[i].x * 8);
    }
    float acc[8] = {0.f, 0.f, 0.f, 0.f, 0.f, 0.f, 0.f, 0.f};
    #pragma unroll
    for (int i = 0; i < 8; ++i) {
        int p = s3 + i * 8;
        if (p < dn) {
            float tv[8];
            unpack8(rq[i], tv);
            float w = __int_as_float(q[i].y);
            #pragma unroll
            for (int j = 0; j < 8; ++j) acc[j] = fmaf(w, tv[j], acc[j]);
        }
    }
    #pragma unroll
    for (int d = 1; d < 8; d <<= 1) {
        #pragma unroll
        for (int j = 0; j < 8; ++j) acc[j] += __shfl_xor(acc[j], d, 64);
    }
    uint4 qh = *(const uint4*)(xbf + (long long)n * 8);
    float h[8];
    unpack8(qh, h);
    float o = sb[s3];
    #pragma unroll
    for (int i = 0; i < 7; ++i)
        o = fmaf(acc[i], swr[i * 8 + s3], fmaf(h[i], swo[i * 8 + s3], o));
    h2[(long long)n * 8 + s3] = f2bf(o);
}

// ---------------- bf16 gather (L2-L4): agg[n][FIN] = sum w_e*hin[src] ------
// FIN = 8<<LOGF; CHUNKS x SPLIT lanes per node; full prefetch (<=8/lane).
template<int LOGF, int SLOG>
__global__ __launch_bounds__(256) void gather_bf16(const u16* __restrict__ hin,
                                                   const int* __restrict__ deg,
                                                   const int2* __restrict__ pair,
                                                   u16* __restrict__ agg) {
    constexpr int FIN = 8 << LOGF;
    constexpr int S = 1 << SLOG;
    constexpr int MAXIT = BCAP / S;
    long long tid = (long long)blockIdx.x * 256 + threadIdx.x;
    int n = (int)(tid >> (LOGF + SLOG));
    if (n >= N_NODES) return;
    int sub = (int)(tid & ((1 << (LOGF + SLOG)) - 1));
    int c = sub & ((1 << LOGF) - 1);
    int half = sub >> LOGF;
    const u16* base = hin + c * 8;
    int dn = deg[n]; if (dn > BCAP) dn = BCAP;
    const int2* row = pair + (long long)n * BCAP;

    int2 q[MAXIT];
    #pragma unroll
    for (int i = 0; i < MAXIT; ++i) {
        int p = half + i * S;
        if (p < dn) q[i] = row[p];
    }
    uint4 rq[MAXIT];
    #pragma unroll
    for (int i = 0; i < MAXIT; ++i) {
        int p = half + i * S;
        if (p < dn) rq[i] = *(const uint4*)(base + (long long)q[i].x * FIN);
    }
    float acc[8] = {0.f, 0.f, 0.f, 0.f, 0.f, 0.f, 0.f, 0.f};
    #pragma unroll
    for (int i = 0; i < MAXIT; ++i) {
        int p = half + i * S;
        if (p < dn) {
            float tv[8];
            unpack8(rq[i], tv);
            float w = __int_as_float(q[i].y);
            #pragma unroll
            for (int j = 0; j < 8; ++j) acc[j] = fmaf(w, tv[j], acc[j]);
        }
    }
    #pragma unroll
    for (int d = (1 << LOGF); d < (1 << (LOGF + SLOG)); d <<= 1) {
        #pragma unroll
        for (int j = 0; j < 8; ++j) acc[j] += __shfl_xor(acc[j], d, 64);
    }
    if (half == 0) {
        uint4 o;
        o.x = packpair(acc[0], acc[1]); o.y = packpair(acc[2], acc[3]);
        o.z = packpair(acc[4], acc[5]); o.w = packpair(acc[6], acc[7]);
        *(uint4*)(agg + (long long)n * FIN + c * 8) = o;
    }
}

// ---------------- L5 gather fused with pooling: S_rel += gather ------------
// FIN=64; 64 lanes per node (8 chunks x 8 split). After butterfly reduce,
// redistribute so lane f holds feature f; one coalesced atomic per lane.
__global__ __launch_bounds__(256) void gather_pool5(const u16* __restrict__ h5,
                                                    const int* __restrict__ deg,
                                                    const int2* __restrict__ pair,
                                                    const int* __restrict__ batch,
                                                    float* __restrict__ S_rel) {
    long long tid = (long long)blockIdx.x * 256 + threadIdx.x;
    int n = (int)(tid >> 6);
    if (n >= N_NODES) return;
    int lane = (int)(tid & 63);
    int c = lane & 7;
    int half = lane >> 3;
    const u16* base = h5 + c * 8;
    int dn = deg[n]; if (dn > BCAP) dn = BCAP;
    const int2* row = pair + (long long)n * BCAP;

    int2 q[8];
    #pragma unroll
    for (int i = 0; i < 8; ++i) {
        int p = half + i * 8;
        if (p < dn) q[i] = row[p];
    }
    uint4 rq[8];
    #pragma unroll
    for (int i = 0; i < 8; ++i) {
        int p = half + i * 8;
        if (p < dn) rq[i] = *(const uint4*)(base + (long long)q[i].x * 64);
    }
    float acc[8] = {0.f, 0.f, 0.f, 0.f, 0.f, 0.f, 0.f, 0.f};
    #pragma unroll
    for (int i = 0; i < 8; ++i) {
        int p = half + i * 8;
        if (p < dn) {
            float tv[8];
            unpack8(rq[i], tv);
            float w = __int_as_float(q[i].y);
            #pragma unroll
            for (int j = 0; j < 8; ++j) acc[j] = fmaf(w, tv[j], acc[j]);
        }
    }
    #pragma unroll
    for (int d = 8; d < 64; d <<= 1) {
        #pragma unroll
        for (int j = 0; j < 8; ++j) acc[j] += __shfl_xor(acc[j], d, 64);
    }
    // redistribute: lane f wants acc[f&7] from lane (f>>3)
    float val = 0.f;
    #pragma unroll
    for (int j = 0; j < 8; ++j) {
        float t = __shfl(acc[j], lane >> 3, 64);
        if ((lane & 7) == j) val = t;
    }
    int g = batch[n];
    atomicAdd(&S_rel[g * 64 + lane], val);
}

// ---------------- MFMA node update; optional S_root/cnt pool (L4) ----------
// One wave per 16-node M-tile; A: k<FIN from agg, FIN<=k<2FIN from hin.
// D map (m89-verified): col = lane&15, row = (lane>>4)*4 + r.
template<int FIN, int FOUT, bool POOL>
__global__ __launch_bounds__(64) void node_mfma(const u16* __restrict__ agg,
                                                const u16* __restrict__ hin,
                                                const u16* __restrict__ bpack,
                                                const float* __restrict__ b_rel,
                                                u16* __restrict__ hout,
                                                const int* __restrict__ batch,
                                                float* __restrict__ S_root,
                                                float* __restrict__ cnt) {
    constexpr int KREAL = 2 * FIN;
    constexpr int K = (KREAL < 32) ? 32 : KREAL;
    constexpr int KS = K / 32;
    constexpr int NT = FOUT / 16;
    int lane = threadIdx.x;
    int tile = blockIdx.x;               // 0..2499
    int col = lane & 15;
    int node_a = tile * 16 + col;
    int kgrp = (lane >> 4) * 8;

    f32x4 acc[NT];
    #pragma unroll
    for (int nt = 0; nt < NT; ++nt) {
        float bv = b_rel[nt * 16 + col];
        acc[nt] = (f32x4){bv, bv, bv, bv};
    }

    #pragma unroll
    for (int ks = 0; ks < KS; ++ks) {
        int k0 = ks * 32 + kgrp;
        bf16x8 af;
        if (k0 < FIN)
            af = *(const bf16x8*)(agg + (long long)node_a * FIN + k0);
        else if (k0 < KREAL)
            af = *(const bf16x8*)(hin + (long long)node_a * FIN + (k0 - FIN));
        else
            af = (bf16x8)(short)0;
        #pragma unroll
        for (int nt = 0; nt < NT; ++nt) {
            bf16x8 bf = *(const bf16x8*)(bpack + (((nt * KS + ks) << 6) + lane) * 8);
            acc[nt] = __builtin_amdgcn_mfma_f32_16x16x32_bf16(af, bf, acc[nt], 0, 0, 0);
        }
    }

    int row0 = tile * 16 + (lane >> 4) * 4;
    #pragma unroll
    for (int nt = 0; nt < NT; ++nt)
        #pragma unroll
        for (int r = 0; r < 4; ++r)
            hout[(long long)(row0 + r) * FOUT + nt * 16 + col] = f2bf(acc[nt][r]);

    if constexpr (POOL) {
        int b_first = batch[tile * 16];
        int b_last = batch[tile * 16 + 15];
        if (b_first == b_last) {
            #pragma unroll
            for (int nt = 0; nt < NT; ++nt) {
                float s = acc[nt][0] + acc[nt][1] + acc[nt][2] + acc[nt][3];
                s += __shfl_xor(s, 16, 64);
                s += __shfl_xor(s, 32, 64);
                if (lane < 16) atomicAdd(&S_root[b_first * FOUT + nt * 16 + col], s);
            }
            if (lane == 0) atomicAdd(&cnt[b_first], 16.f);
        } else {
            #pragma unroll
            for (int r = 0; r < 4; ++r) {
                int g = batch[row0 + r];
                #pragma unroll
                for (int nt = 0; nt < NT; ++nt)
                    atomicAdd(&S_root[g * FOUT + nt * 16 + col], acc[nt][r]);
                if (col == 0) atomicAdd(&cnt[g], 1.f);
            }
        }
    }
}

// ---------------- classifier: out = [S_rel|S_root]@M + cnt*bb + b_lin ------
__global__ void final_kernel(const float* __restrict__ S_rel,
                             const float* __restrict__ S_root,
                             const float* __restrict__ cnt,
                             const float* __restrict__ M,
                             const float* __restrict__ bb,
                             const float* __restrict__ b_lin,
                             float* __restrict__ out) {
    int tid = threadIdx.x;  // 128 threads: (graph, class)
    int g = tid >> 1;
    int c = tid & 1;
    float acc = b_lin[c] + cnt[g] * bb[c];
    #pragma unroll 8
    for (int k = 0; k < 64; ++k) {
        acc += S_rel[g * 64 + k] * M[k * 2 + c];
        acc += S_root[g * 64 + k] * M[(64 + k) * 2 + c];
    }
    out[g * 2 + c] = acc;
}

extern "C" void kernel_launch(void* const* d_in, const int* in_sizes, int n_in,
                              void* d_out, int out_size, void* d_ws, size_t ws_size,
                              hipStream_t stream) {
    const float* x     = (const float*)d_in[0];
    const int*   ei    = (const int*)d_in[1];
    const float* ea    = (const float*)d_in[2];
    const int*   batch = (const int*)d_in[3];
    const int* src = ei;
    const int* dst = ei + N_EDGES;

    const float* w_rel[5], *b_rel[5], *w_root[5];
    for (int i = 0; i < 5; ++i) {
        w_rel[i]  = (const float*)d_in[4 + 3 * i];
        b_rel[i]  = (const float*)d_in[5 + 3 * i];
        w_root[i] = (const float*)d_in[6 + 3 * i];
    }
    const float* w_lin = (const float*)d_in[19];
    const float* b_lin = (const float*)d_in[20];
    float* out = (float*)d_out;

    // ---- workspace layout (all sections 16B-aligned) ----
    u16*   xbf     = (u16*)d_ws;                  // 40000*8
    u16*   agg     = xbf + 320000;                // 40000*32 (L2-L4 max)
    u16*   h2      = agg + 1280000;               // 40000*8
    u16*   h3      = h2 + 320000;                 // 40000*16
    u16*   h4      = h3 + 640000;                 // 40000*32
    u16*   h5      = h4 + 1280000;                // 40000*64
    u16*   p2      = h5 + 2560000;                // 512
    u16*   p3      = p2 + 512;                    // 1024
    u16*   p4      = p3 + 1024;                   // 4096
    float* S_rel   = (float*)(p4 + 4096);         // 4096
    float* S_root  = S_rel + 4096;                // 4096
    float* cnt     = S_root + 4096;               // 64
    float* M       = cnt + 64;                    // 256
    float* bb      = M + 256;                     // 2 (+2 pad)
    int2*  pair    = (int2*)(bb + 4);             // 40000*BCAP (20.5 MB)
    int*   deg     = (int*)(pair + (long long)N_NODES * BCAP);  // 40000

    const int BLK = 256;
    const int EB = cdiv(N_EDGES, BLK);

    // ---- prep (convert x, pack w2-4, zero deg/S, M = Wstk5@w_lin) ----
    prep_kernel<<<368, BLK, 0, stream>>>(x, xbf,
                                         w_rel[1], w_root[1], w_rel[2], w_root[2],
                                         w_rel[3], w_root[3], w_rel[4], w_root[4],
                                         b_rel[4], w_lin,
                                         p2, p3, p4, deg, S_rel, M, bb);

    // ---- bucket CSR: single one-pass scatter ----
    scatter_bucket<<<EB, BLK, 0, stream>>>(src, dst, ea, deg, pair);

    // ---- layer 1: 7 -> 8 (fused gather + node update) ----
    gather_node1<<<1250, BLK, 0, stream>>>(xbf, deg, pair, w_rel[0], b_rel[0], w_root[0], h2);

    // ---- layer 2: 8 -> 16 (MFMA, K padded to 32) ----
    gather_bf16<0, 3><<<cdiv((long long)N_NODES * 8, BLK), BLK, 0, stream>>>(
        h2, deg, pair, agg);
    node_mfma<8, 16, false><<<2500, 64, 0, stream>>>(agg, h2, p2, b_rel[1], h3,
                                                     nullptr, nullptr, nullptr);

    // ---- layer 3: 16 -> 32 (MFMA) ----
    gather_bf16<1, 3><<<cdiv((long long)N_NODES * 16, BLK), BLK, 0, stream>>>(
        h3, deg, pair, agg);
    node_mfma<16, 32, false><<<2500, 64, 0, stream>>>(agg, h3, p3, b_rel[2], h4,
                                                      nullptr, nullptr, nullptr);

    // ---- layer 4: 32 -> 64 (MFMA, S_root/cnt pooled in epilogue) ----
    gather_bf16<2, 3><<<cdiv((long long)N_NODES * 32, BLK), BLK, 0, stream>>>(
        h4, deg, pair, agg);
    node_mfma<32, 64, true><<<2500, 64, 0, stream>>>(agg, h4, p4, b_rel[3], h5,
                                                     batch, S_root, cnt);

    // ---- layer 5 gather fused with S_rel pooling (no L5 GEMM, no seg_pool) ----
    gather_pool5<<<10000, BLK, 0, stream>>>(h5, deg, pair, batch, S_rel);

    // ---- classifier ----
    final_kernel<<<1, 128, 0, stream>>>(S_rel, S_root, cnt, M, bb, b_lin, out);
}